// Round 2
// baseline (2153.384 us; speedup 1.0000x reference)
//
#include <hip/hip_runtime.h>
#include <math.h>

#define TPB 256
#define EPS_GAP 5e-4f

// ---------------- shared scan machinery (fp32 fast / f64 rescue) ----------------

// Argmax over 2*dot(root, x) for all 240 E8 roots, first-index-wins ties.
// (d2 = |x|^2 + 2 - 2dot: the |x|^2+2 term is common to all candidates, so
//  argmin d2 == argmax 2dot. Uniform positive scaling of x is order-invariant,
//  so fp32 error in the scale/decay powers cannot flip a decision — only
//  additive noise can, which the T2 gap-flag guards.)
template<typename F, bool T2>
__device__ __forceinline__ int scan_level(const F* x, bool& flag){
    F best = (F)(-1e30), best2 = (F)(-1e30);
    int bidx = 0;
    auto cand = [&](F s, int iv){
        if (T2){ F mn = s < best ? s : best; best2 = mn > best2 ? mn : best2; }
        if (s > best){ best = s; bidx = iv; }
    };
    // 112 pair roots (+-1,+-1,0^6): 2dot = 2(+-x_i +- x_j)
    #pragma unroll
    for (int i=0;i<8;i++){
        #pragma unroll
        for (int j=i+1;j<8;j++){
            const int pb = 4*(7*i - (i*(i-1))/2 + (j-i-1));
            F p2 = (F)2*(x[i]+x[j]);
            F m2 = (F)2*(x[i]-x[j]);
            cand(p2, pb); cand(m2, pb+1); cand(-m2, pb+2); cand(-p2, pb+3);
        }
    }
    // 128 half roots (+-1/2)^8 even parity: 2dot = lo16[b&15] + hi16[b>>4]
    {
        F e01p=x[0]+x[1], e01m=x[0]-x[1];
        F e23p=x[2]+x[3], e23m=x[2]-x[3];
        F e45p=x[4]+x[5], e45m=x[4]-x[5];
        F e67p=x[6]+x[7], e67m=x[6]-x[7];
        F s01[4]={e01p,-e01m,e01m,-e01p};
        F s23[4]={e23p,-e23m,e23m,-e23p};
        F s45[4]={e45p,-e45m,e45m,-e45p};
        F s67[4]={e67p,-e67m,e67m,-e67p};
        F lo16[16], hi16[16];
        #pragma unroll
        for (int p=0;p<16;p++){ lo16[p]=s01[p&3]+s23[(p>>2)&3]; hi16[p]=s45[p&3]+s67[(p>>2)&3]; }
        #pragma unroll
        for (int b=0;b<256;b++){
            if (__builtin_popcount(b)&1) continue;
            cand(lo16[b&15]+hi16[b>>4], 112+(b>>1));
        }
    }
    if (T2) flag = flag || ((best - best2) < (F)EPS_GAP);
    return bidx;
}

template<typename F>
__device__ __forceinline__ void apply_root(int bidx, F scale, F* residual){
    int p = bidx>>2, sgn = bidx&3;
    int gi = (p>=7)+(p>=13)+(p>=18)+(p>=22)+(p>=25)+(p>=27);
    int basep = 0;
    basep = p>=7 ? 7 : basep;
    basep = p>=13? 13: basep;
    basep = p>=18? 18: basep;
    basep = p>=22? 22: basep;
    basep = p>=25? 25: basep;
    basep = p>=27? 27: basep;
    int gj = gi + 1 + (p - basep);
    F sI = (sgn&2)? (F)-1:(F)1;
    F sJ = (sgn&1)? (F)-1:(F)1;
    int hb = (bidx-112)<<1;
    hb |= (__builtin_popcount(hb)&1);        // restore even parity
    bool isPair = bidx < 112;
    #pragma unroll
    for (int k=0;k<8;k++){
        F cp = ((k==gi)? sI:(F)0) + ((k==gj)? sJ:(F)0);
        F ch = ((hb>>k)&1)? (F)-0.5:(F)0.5;
        F coef = isPair? cp : ch;
        residual[k] -= coef*scale;
    }
}

// ---------------- phase B/C: softmax+gathers+refine (fp32, shared) ----------------
// T = per-thread LDS region, 24 slots used: [0..7]=q, [8..23]=lo16 tables.
__device__ __forceinline__ void phaseBC(float* T, const float* qf,
    int i1,int i2,int i3,int i4,int i5,int i6,int i7, float decay,
    const float* __restrict__ lemb, const float* __restrict__ bcp,
    const float* __restrict__ rcpar, const float* __restrict__ bcx,
    const float* __restrict__ rw1, const float* __restrict__ rb1,
    const float* __restrict__ rw2, const float* __restrict__ rb2,
    const float* __restrict__ rgate, float* __restrict__ orow)
{
    const float IS2   = 0.70710678118654752f;   // 1/sqrt2
    const float HS2   = 0.35355339059327376f;   // 0.5/sqrt2
    const float LOG2F = 0.69314718055994531f;

    float hi16[16];                             // registers (constant-indexed)
    {
        float a01p=qf[0]+qf[1], a01m=qf[0]-qf[1];
        float a23p=qf[2]+qf[3], a23m=qf[2]-qf[3];
        float a45p=qf[4]+qf[5], a45m=qf[4]-qf[5];
        float a67p=qf[6]+qf[7], a67m=qf[6]-qf[7];
        float s01[4]={a01p,-a01m,a01m,-a01p};
        float s23[4]={a23p,-a23m,a23m,-a23p};
        float s45[4]={a45p,-a45m,a45m,-a45p};
        float s67[4]={a67p,-a67m,a67m,-a67p};
        #pragma unroll
        for (int p=0;p<16;p++){ T[8+p]=s01[p&3]+s23[(p>>2)&3]; hi16[p]=s45[p&3]+s67[(p>>2)&3]; }
        #pragma unroll
        for (int k=0;k<8;k++) T[k]=qf[k];
    }

    float emb[52], ctl[4], den=0.f;
    #pragma unroll
    for (int k=0;k<52;k++) emb[k]=0.f;
    ctl[0]=ctl[1]=ctl[2]=ctl[3]=0.f;

    auto proc = [&](float sims, int j){
        float e = __expf(sims - bcx[j]*LOG2F);  // logits bounded by sqrt2; exp safe
        den += e;
        const float* ep = lemb + j*52;          // wave-uniform j -> scalar loads
        #pragma unroll
        for (int k=0;k<52;k++) emb[k] = fmaf(e, ep[k], emb[k]);
        const float* cq = bcp + j*4;
        #pragma unroll
        for (int k=0;k<4;k++) ctl[k] = fmaf(e, cq[k], ctl[k]);
    };

    // half roots: outer nibble h unrolled (hi16 const-indexed), inner rolled via LDS lo16
    #pragma unroll
    for (int h=0;h<16;h++){
        float hv = hi16[h];
        int ph = __builtin_popcount(h)&1;
        for (int m=0;m<8;m++){
            int lo = (m<<1) | ((__builtin_popcount(m)&1)^ph);
            proc((T[8+lo]+hv)*HS2, 112 + (h<<3) + m);
        }
    }
    // pair roots (q components via LDS, runtime ii/jn)
    {
        int ii=0, jn=1;
        for (int pc=0;pc<28;++pc){
            float a=T[ii], b=T[jn];
            float p=a+b, mm=a-b;
            proc( p*IS2, 4*pc+0);
            proc( mm*IS2,4*pc+1);
            proc(-mm*IS2,4*pc+2);
            proc(-p*IS2, 4*pc+3);
            if (++jn==8){ ++ii; jn=ii+1; }
        }
    }
    float rden = 1.f/den;
    #pragma unroll
    for (int k=0;k<52;k++) emb[k] *= rden;
    #pragma unroll
    for (int k=0;k<4;k++) ctl[k] *= rden;

    // hard-index gathers, levels 1..7 (per-lane vector loads, L2-resident)
    {
        float dp = decay;
        #define DO_G(LVL, IV) { \
            float ild = 1.0f/dp; \
            const float* ep = lemb + ((size_t)(LVL)*240 + (size_t)(IV))*52; \
            const float* cq = rcpar + ((size_t)((LVL)-1)*240 + (size_t)(IV))*4; \
            _Pragma("unroll") for (int k=0;k<52;k++) emb[k] = fmaf(ild, ep[k], emb[k]); \
            _Pragma("unroll") for (int k=0;k<4;k++) ctl[k] = fmaf(ild, cq[k], ctl[k]); \
            dp *= decay; }
        DO_G(1,i1) DO_G(2,i2) DO_G(3,i3) DO_G(4,i4) DO_G(5,i5) DO_G(6,i6) DO_G(7,i7)
        #undef DO_G
    }

    // gated refinement MLP
    float rf[52];
    #pragma unroll
    for (int m_=0;m_<52;m_++) rf[m_]=rb2[m_];
    for (int k=0;k<52;k++){
        float a = rb1[k];
        #pragma unroll
        for (int j=0;j<52;j++) a = fmaf(rw1[k*52+j], emb[j], a);
        float t = 0.5f*a*(1.f+erff(a*0.70710678f));
        #pragma unroll
        for (int m_=0;m_<52;m_++) rf[m_] = fmaf(t, rw2[m_*52+k], rf[m_]);
    }
    float sg = 1.f/(1.f+__expf(-rgate[0]));
    #pragma unroll
    for (int m_=0;m_<52;m_++) emb[m_] = fmaf(sg, rf[m_], emb[m_]);

    float4* o4 = (float4*)orow;
    #pragma unroll
    for (int t=0;t<13;t++)
        o4[t] = make_float4(emb[4*t], emb[4*t+1], emb[4*t+2], emb[4*t+3]);
    o4[13] = make_float4(ctl[0], ctl[1], ctl[2], ctl[3]);
}

// ---------------- kernel 1: fp32 fast path + near-tie flagging ----------------
__global__ __launch_bounds__(TPB,4) void e8_fast(
    const float* __restrict__ g_obs,
    const float* __restrict__ pw1, const float* __restrict__ pb1,
    const float* __restrict__ pw2, const float* __restrict__ pb2,
    const float* __restrict__ lemb, const float* __restrict__ bcp,
    const float* __restrict__ rcpar, const float* __restrict__ bcx,
    const float* __restrict__ glogdecay,
    const float* __restrict__ rw1, const float* __restrict__ rb1,
    const float* __restrict__ rw2, const float* __restrict__ rb2,
    const float* __restrict__ rgate,
    unsigned char* __restrict__ flags, float* __restrict__ out, int B)
{
    __shared__ float smem[TPB*25];   // stride 25: gcd(25,32)=1 -> conflict-free
    const int tid = threadIdx.x;
    const int row = blockIdx.x*TPB + tid;

    {   // coalesced obs staging
        const size_t base = (size_t)blockIdx.x*TPB*14;
        const size_t lim  = (size_t)B*14;
        for (int t = tid; t < TPB*14; t += TPB){
            size_t g = base + (size_t)t;
            smem[t] = (g < lim) ? g_obs[g] : 0.f;
        }
    }
    __syncthreads();
    const bool active = row < B;

    float qf[8];
    int i1=0,i2=0,i3=0,i4=0,i5=0,i6=0,i7=0;
    float decay = 1.f;

    if (active){
        float ob[14];
        #pragma unroll
        for (int j=0;j<14;j++) ob[j]=smem[tid*14+j];
        float qa[8];
        #pragma unroll
        for (int m=0;m<8;m++) qa[m]=pb2[m];
        for (int k=0;k<32;k++){
            float a = pb1[k];
            #pragma unroll
            for (int j=0;j<14;j++) a = fmaf(pw1[k*14+j], ob[j], a);
            float h = 0.5f*a*(1.f+erff(a*0.70710678f));
            #pragma unroll
            for (int m=0;m<8;m++) qa[m] = fmaf(pw2[m*32+k], h, qa[m]);
        }
        float n2=0.f;
        #pragma unroll
        for (int m=0;m<8;m++) n2 = fmaf(qa[m],qa[m],n2);
        float nr = sqrtf(n2); nr = fmaxf(nr, 1e-12f);
        float sc = 1.41421356237309505f/nr;
        float residual[8];
        #pragma unroll
        for (int m=0;m<8;m++){ qf[m]=qa[m]*sc; residual[m]=qf[m]; }

        decay = expf(glogdecay[0]);
        float dpow = 1.f;
        bool flag = false;
        int lastIdx;

        for (int lvl=0; lvl<3; ++lvl){          // protected levels: track top-2 gap
            float rs = dpow*0.5f;
            float x[8];
            #pragma unroll
            for (int k=0;k<8;k++) x[k]=residual[k]*rs;
            lastIdx = scan_level<float,true>(x, flag);
            apply_root<float>(lastIdx, 2.f/dpow, residual);
            if (lvl==1) i1=lastIdx; else if (lvl==2) i2=lastIdx;
            dpow *= decay;
        }
        for (int lvl=3; lvl<8; ++lvl){          // deep levels: flips are < 1e-5 in output
            float rs = dpow*0.5f;
            float x[8];
            #pragma unroll
            for (int k=0;k<8;k++) x[k]=residual[k]*rs;
            bool dummy=false;
            lastIdx = scan_level<float,false>(x, dummy);
            apply_root<float>(lastIdx, 2.f/dpow, residual);
            if (lvl==3) i3=lastIdx; else if (lvl==4) i4=lastIdx;
            else if (lvl==5) i5=lastIdx; else if (lvl==6) i6=lastIdx; else i7=lastIdx;
            dpow *= decay;
        }
        flags[row] = flag ? 1 : 0;
    }

    __syncthreads();   // obs region of smem now reusable as per-thread tables
    if (active)
        phaseBC(smem + tid*25, qf, i1,i2,i3,i4,i5,i6,i7, decay,
                lemb,bcp,rcpar,bcx,rw1,rb1,rw2,rb2,rgate, out + (size_t)row*56);
}

// ---------------- kernel 2: f64 rescue for near-tie rows ----------------
__global__ __launch_bounds__(TPB) void e8_rescue(
    const float* __restrict__ g_obs,
    const float* __restrict__ pw1, const float* __restrict__ pb1,
    const float* __restrict__ pw2, const float* __restrict__ pb2,
    const float* __restrict__ lemb, const float* __restrict__ bcp,
    const float* __restrict__ rcpar, const float* __restrict__ bcx,
    const float* __restrict__ glogdecay,
    const float* __restrict__ rw1, const float* __restrict__ rb1,
    const float* __restrict__ rw2, const float* __restrict__ rb2,
    const float* __restrict__ rgate,
    const unsigned char* __restrict__ flags, float* __restrict__ out, int B)
{
    __shared__ float smem[TPB*25];
    const int tid = threadIdx.x;
    const int row = blockIdx.x*TPB + tid;
    bool f = (row < B) && (flags[row] != 0);
    if (__ballot(f) == 0ull) return;            // whole wave clean -> cheap exit
    if (!f) return;

    double ob[14];
    #pragma unroll
    for (int j=0;j<14;j++) ob[j] = (double)g_obs[(size_t)row*14+j];
    double qa[8];
    #pragma unroll
    for (int m=0;m<8;m++) qa[m] = (double)pb2[m];
    for (int k=0;k<32;k++){
        double a = (double)pb1[k];
        #pragma unroll
        for (int j=0;j<14;j++) a += (double)pw1[k*14+j]*ob[j];
        double hk = 0.5*a*(1.0 + erf(a*0.70710678118654752440));
        #pragma unroll
        for (int m=0;m<8;m++) qa[m] += (double)pw2[m*32+k]*hk;
    }
    double n2 = 0.0;
    #pragma unroll
    for (int m=0;m<8;m++) n2 += qa[m]*qa[m];
    double nr = sqrt(n2); if (nr < 1e-12) nr = 1e-12;
    double q[8], residual[8];
    #pragma unroll
    for (int m=0;m<8;m++){ q[m] = qa[m]/nr*1.4142135623730951; residual[m]=q[m]; }

    double decay_d = exp((double)glogdecay[0]);
    double dpow = 1.0;
    int i1=0,i2=0,i3=0,i4=0,i5=0,i6=0,i7=0;
    bool dummy=false;
    for (int lvl=0; lvl<8; ++lvl){
        double rs = dpow*0.5;
        double x[8];
        #pragma unroll
        for (int k=0;k<8;k++) x[k]=residual[k]*rs;
        int lastIdx = scan_level<double,false>(x, dummy);
        apply_root<double>(lastIdx, 2.0/dpow, residual);
        if      (lvl==1) i1=lastIdx; else if (lvl==2) i2=lastIdx;
        else if (lvl==3) i3=lastIdx; else if (lvl==4) i4=lastIdx;
        else if (lvl==5) i5=lastIdx; else if (lvl==6) i6=lastIdx;
        else if (lvl==7) i7=lastIdx;
        dpow *= decay_d;
    }
    float qf[8];
    #pragma unroll
    for (int m=0;m<8;m++) qf[m]=(float)q[m];
    phaseBC(smem + tid*25, qf, i1,i2,i3,i4,i5,i6,i7, (float)decay_d,
            lemb,bcp,rcpar,bcx,rw1,rb1,rw2,rb2,rgate, out + (size_t)row*56);
}

extern "C" void kernel_launch(void* const* d_in, const int* in_sizes, int n_in,
                              void* d_out, int out_size, void* d_ws, size_t ws_size,
                              hipStream_t stream)
{
    const float* obs  = (const float*)d_in[0];
    const float* pw1  = (const float*)d_in[1];
    const float* pb1  = (const float*)d_in[2];
    const float* pw2  = (const float*)d_in[3];
    const float* pb2  = (const float*)d_in[4];
    const float* lemb = (const float*)d_in[5];
    const float* bcp  = (const float*)d_in[6];
    const float* rcp  = (const float*)d_in[7];
    const float* bcx  = (const float*)d_in[8];
    const float* ld   = (const float*)d_in[9];
    const float* rw1  = (const float*)d_in[10];
    const float* rb1  = (const float*)d_in[11];
    const float* rw2  = (const float*)d_in[12];
    const float* rb2  = (const float*)d_in[13];
    const float* rg   = (const float*)d_in[14];

    int B = in_sizes[0] / 14;
    int grid = (B + TPB - 1) / TPB;
    unsigned char* flags = (unsigned char*)d_ws;

    e8_fast<<<grid, TPB, 0, stream>>>(obs, pw1, pb1, pw2, pb2, lemb, bcp, rcp, bcx, ld,
                                      rw1, rb1, rw2, rb2, rg, flags, (float*)d_out, B);
    e8_rescue<<<grid, TPB, 0, stream>>>(obs, pw1, pb1, pw2, pb2, lemb, bcp, rcp, bcx, ld,
                                        rw1, rb1, rw2, rb2, rg, flags, (float*)d_out, B);
}

// Round 3
// 565.060 us; speedup vs baseline: 3.8109x; 3.8109x over previous
//
#include <hip/hip_runtime.h>
#include <math.h>

#define TPB 256
#define EPS_GAP 5e-4f

typedef unsigned int u32;
typedef unsigned long long u64;

// ============ exhaustive f64 scan (rescue only; exact np argmin tiebreak) ======
__device__ __forceinline__ int scan_exact_f64(const double* x){
    double best = -1e300; int bidx = 0;
    auto cand = [&](double s, int iv){ if (s > best){ best = s; bidx = iv; } };
    #pragma unroll
    for (int i=0;i<8;i++){
        #pragma unroll
        for (int j=i+1;j<8;j++){
            const int pb = 4*(7*i - (i*(i-1))/2 + (j-i-1));
            double p2 = 2.0*(x[i]+x[j]);
            double m2 = 2.0*(x[i]-x[j]);
            cand(p2, pb); cand(m2, pb+1); cand(-m2, pb+2); cand(-p2, pb+3);
        }
    }
    {
        double e01p=x[0]+x[1], e01m=x[0]-x[1];
        double e23p=x[2]+x[3], e23m=x[2]-x[3];
        double e45p=x[4]+x[5], e45m=x[4]-x[5];
        double e67p=x[6]+x[7], e67m=x[6]-x[7];
        double s01[4]={e01p,-e01m,e01m,-e01p};
        double s23[4]={e23p,-e23m,e23m,-e23p};
        double s45[4]={e45p,-e45m,e45m,-e45p};
        double s67[4]={e67p,-e67m,e67m,-e67p};
        double lo16[16], hi16[16];
        #pragma unroll
        for (int p=0;p<16;p++){ lo16[p]=s01[p&3]+s23[(p>>2)&3]; hi16[p]=s45[p&3]+s67[(p>>2)&3]; }
        #pragma unroll
        for (int b=0;b<256;b++){
            if (__builtin_popcount(b)&1) continue;
            cand(lo16[b&15]+hi16[b>>4], 112+(b>>1));
        }
    }
    return bidx;
}

__device__ __forceinline__ void apply_root_f64(int bidx, double scale, double* residual){
    int p = bidx>>2, sgn = bidx&3;
    int gi = (p>=7)+(p>=13)+(p>=18)+(p>=22)+(p>=25)+(p>=27);
    int basep = 0;
    basep = p>=7 ? 7 : basep;  basep = p>=13? 13: basep;
    basep = p>=18? 18: basep;  basep = p>=22? 22: basep;
    basep = p>=25? 25: basep;  basep = p>=27? 27: basep;
    int gj = gi + 1 + (p - basep);
    double sI = (sgn&2)? -1.0:1.0;
    double sJ = (sgn&1)? -1.0:1.0;
    int hb = (bidx-112)<<1;
    hb |= (__builtin_popcount(hb)&1);
    bool isPair = bidx < 112;
    #pragma unroll
    for (int k=0;k<8;k++){
        double cp = ((k==gi)? sI:0.0) + ((k==gj)? sJ:0.0);
        double ch = ((hb>>k)&1)? -0.5:0.5;
        residual[k] -= (isPair? cp : ch)*scale;
    }
}

// ============ analytic fp32 scan: O(8) instead of O(240) ======================
// argmin d2 == argmax 2*dot(root,x). Pair family best = top-2 |x| with
// matching signs; half family best = sign pattern (parity-fixed at min |x|).
// Runner-up (for the near-tie flag): pair = t1+t3; half = flip-two-smallest /
// flip-only-second-smallest. Exact ties land in the flag -> f64 rescue.
__device__ __forceinline__ int scan_fast(const float* x, float scale,
                                         float* residual, bool protect, bool& flag){
    float aa[8]; int neg=0; float S=0.f;
    #pragma unroll
    for (int k=0;k<8;k++){
        float v=x[k]; float av=fabsf(v);
        aa[k]=av; S+=av; neg |= (v<0.f)?(1<<k):0;
    }
    float t1=-1e30f,t2=-1e30f,t3=-1e30f; int p1=0,p2=0;
    #pragma unroll
    for (int k=0;k<8;k++){
        float v=aa[k];
        bool g1=v>t1, g2=v>t2, g3=v>t3;
        t3 = g2 ? t2 : (g3 ? v : t3);
        t2 = g1 ? t1 : (g2 ? v : t2);
        p2 = g1 ? p1 : (g2 ? k : p2);
        t1 = g1 ? v : t1;
        p1 = g1 ? k : p1;
    }
    float n1=1e30f,n2v=1e30f; int m1=0;
    #pragma unroll
    for (int k=0;k<8;k++){
        float v=aa[k];
        bool l1=v<n1, l2=v<n2v;
        n2v = l1 ? n1 : (l2 ? v : n2v);
        n1  = l1 ? v : n1;
        m1  = l1 ? k : m1;
    }
    int bi = min(p1,p2), bj = max(p1,p2);
    float pv = 2.f*(t1+t2), pr = 2.f*(t1+t3);
    int par = __builtin_popcount((unsigned)neg)&1;
    float hv, hr; int hb;
    if (par==0){ hv=S;          hb=neg;           hr=S-2.f*(n1+n2v); }
    else       { hv=S-2.f*n1;   hb=neg^(1<<m1);   hr=S-2.f*n2v; }
    bool pair = (pv >= hv);                 // tie -> pair (lower index), np-compatible
    float best = pair? pv: hv, alt = pair? hv: pv;
    float second = fmaxf(alt, fmaxf(pr,hr));
    if (protect) flag = flag || ((best-second) < EPS_GAP);
    int s = (((neg>>bi)&1)<<1) | ((neg>>bj)&1);
    int pidx = 4*(7*bi - ((bi*(bi-1))>>1) + (bj-bi-1)) + s;
    int hidx = 112 + (hb>>1);
    // residual update
    float sI = ((neg>>bi)&1)? scale : -scale;     // residual -= coef*scale
    float sJ = ((neg>>bj)&1)? scale : -scale;
    #pragma unroll
    for (int k=0;k<8;k++){
        float cp = ((k==bi)? sI:0.f) + ((k==bj)? sJ:0.f);
        float ch = ((hb>>k)&1)? 0.5f*scale : -0.5f*scale;
        residual[k] += (pair? cp : ch);
    }
    return pair? pidx : hidx;
}

// ============ phase B: softmax over 240 roots + hard gathers (pre-refine) =====
// T = per-thread LDS region (25 slots): [0..7]=q, [8..23]=lo16.
__device__ __forceinline__ void phaseB(float* T, const float* qf,
    int i1,int i2,int i3,int i4,int i5,int i6,int i7, float decay,
    const float* __restrict__ lemb, const float* __restrict__ bcp,
    const float* __restrict__ rcpar, const float* __restrict__ bcx,
    float* __restrict__ orow)
{
    const float IS2 = 0.70710678118654752f;
    const float HS2 = 0.35355339059327376f;
    const float LG2 = 0.69314718055994531f;
    float hi16[16];
    {
        float a01p=qf[0]+qf[1], a01m=qf[0]-qf[1];
        float a23p=qf[2]+qf[3], a23m=qf[2]-qf[3];
        float a45p=qf[4]+qf[5], a45m=qf[4]-qf[5];
        float a67p=qf[6]+qf[7], a67m=qf[6]-qf[7];
        float s01[4]={a01p,-a01m,a01m,-a01p};
        float s23[4]={a23p,-a23m,a23m,-a23p};
        float s45[4]={a45p,-a45m,a45m,-a45p};
        float s67[4]={a67p,-a67m,a67m,-a67p};
        #pragma unroll
        for (int p=0;p<16;p++){ T[8+p]=s01[p&3]+s23[(p>>2)&3]; hi16[p]=s45[p&3]+s67[(p>>2)&3]; }
        #pragma unroll
        for (int k=0;k<8;k++) T[k]=qf[k];
    }
    float emb[52], ctl[4], den=0.f;
    #pragma unroll
    for (int k=0;k<52;k++) emb[k]=0.f;
    ctl[0]=ctl[1]=ctl[2]=ctl[3]=0.f;

    auto proc = [&](float sims, int j){
        float e = __expf(sims - bcx[j]*LG2);   // logits bounded by sqrt2; safe
        den += e;
        const float* ep = lemb + j*52;         // wave-uniform j -> s_loads
        #pragma unroll
        for (int k=0;k<52;k++) emb[k] = fmaf(e, ep[k], emb[k]);
        const float* cq = bcp + j*4;
        #pragma unroll
        for (int k=0;k<4;k++) ctl[k] = fmaf(e, cq[k], ctl[k]);
    };
    #pragma unroll
    for (int h=0;h<16;h++){                    // half roots: hi16 const-indexed
        float hv = hi16[h];
        int ph = __builtin_popcount(h)&1;
        for (int m=0;m<8;m++){
            int lo = (m<<1) | ((__builtin_popcount(m)&1)^ph);
            proc((T[8+lo]+hv)*HS2, 112 + (h<<3) + m);
        }
    }
    {
        int ii=0, jn=1;
        for (int pc=0;pc<28;++pc){             // pair roots via LDS q
            float a=T[ii], b=T[jn];
            float p=a+b, mm=a-b;
            proc( p*IS2, 4*pc+0);
            proc( mm*IS2,4*pc+1);
            proc(-mm*IS2,4*pc+2);
            proc(-p*IS2, 4*pc+3);
            if (++jn==8){ ++ii; jn=ii+1; }
        }
    }
    float rden = 1.f/den;
    #pragma unroll
    for (int k=0;k<52;k++) emb[k] *= rden;
    #pragma unroll
    for (int k=0;k<4;k++) ctl[k] *= rden;

    // hard-index gathers (per-lane float4, L2-resident tables)
    {
        float dp = decay;
        #define DO_G(LVL, IV) { \
            float ild = 1.0f/dp; \
            const float4* ep4 = (const float4*)(lemb + ((size_t)(LVL)*240 + (size_t)(IV))*52); \
            _Pragma("unroll") for (int t4=0;t4<13;t4++){ float4 v=ep4[t4]; \
                emb[4*t4+0]=fmaf(ild,v.x,emb[4*t4+0]); emb[4*t4+1]=fmaf(ild,v.y,emb[4*t4+1]); \
                emb[4*t4+2]=fmaf(ild,v.z,emb[4*t4+2]); emb[4*t4+3]=fmaf(ild,v.w,emb[4*t4+3]); } \
            float4 cv = *(const float4*)(rcpar + ((size_t)((LVL)-1)*240 + (size_t)(IV))*4); \
            ctl[0]=fmaf(ild,cv.x,ctl[0]); ctl[1]=fmaf(ild,cv.y,ctl[1]); \
            ctl[2]=fmaf(ild,cv.z,ctl[2]); ctl[3]=fmaf(ild,cv.w,ctl[3]); \
            dp *= decay; }
        DO_G(1,i1) DO_G(2,i2) DO_G(3,i3) DO_G(4,i4) DO_G(5,i5) DO_G(6,i6) DO_G(7,i7)
        #undef DO_G
    }
    float4* o4 = (float4*)orow;                // pre-refine output
    #pragma unroll
    for (int t=0;t<13;t++)
        o4[t] = make_float4(emb[4*t], emb[4*t+1], emb[4*t+2], emb[4*t+3]);
    o4[13] = make_float4(ctl[0], ctl[1], ctl[2], ctl[3]);
}

// ============ K1: fp32 A+B, flags near-ties, compacts rescue list =============
__global__ __launch_bounds__(TPB) void e8_main(
    const float* __restrict__ g_obs,
    const float* __restrict__ pw1, const float* __restrict__ pb1,
    const float* __restrict__ pw2, const float* __restrict__ pb2,
    const float* __restrict__ lemb, const float* __restrict__ bcp,
    const float* __restrict__ rcpar, const float* __restrict__ bcx,
    const float* __restrict__ glogdecay,
    u32* __restrict__ cnt, u32* __restrict__ list,
    unsigned char* __restrict__ flags, int useCompact,
    float* __restrict__ out, int B)
{
    __shared__ float smem[TPB*25];
    const int tid = threadIdx.x;
    const int row = blockIdx.x*TPB + tid;

    {   // coalesced obs staging
        const size_t base = (size_t)blockIdx.x*TPB*14;
        const size_t lim  = (size_t)B*14;
        for (int t = tid; t < TPB*14; t += TPB){
            size_t g = base + (size_t)t;
            smem[t] = (g < lim) ? g_obs[g] : 0.f;
        }
    }
    __syncthreads();
    const bool active = row < B;

    float qf[8];
    int idxs[8] = {0,0,0,0,0,0,0,0};
    float decay = 1.f;
    bool flag = false;

    if (active){
        float ob[14];
        #pragma unroll
        for (int j=0;j<14;j++) ob[j]=smem[tid*14+j];
        float qa[8];
        #pragma unroll
        for (int m=0;m<8;m++) qa[m]=pb2[m];
        #pragma unroll 1
        for (int k=0;k<32;k++){
            float a = pb1[k];
            #pragma unroll
            for (int j=0;j<14;j++) a = fmaf(pw1[k*14+j], ob[j], a);
            float h = 0.5f*a*(1.f+erff(a*0.70710678f));
            #pragma unroll
            for (int m=0;m<8;m++) qa[m] = fmaf(pw2[m*32+k], h, qa[m]);
        }
        float n2=0.f;
        #pragma unroll
        for (int m=0;m<8;m++) n2 = fmaf(qa[m],qa[m],n2);
        float nr = fmaxf(sqrtf(n2), 1e-12f);
        float sc = 1.41421356237309505f/nr;
        float residual[8];
        #pragma unroll
        for (int m=0;m<8;m++){ qf[m]=qa[m]*sc; residual[m]=qf[m]; }

        decay = expf(glogdecay[0]);
        float dpow = 1.f;
        #pragma unroll
        for (int lvl=0; lvl<8; ++lvl){
            float rs = 0.5f*dpow;
            float x[8];
            #pragma unroll
            for (int k=0;k<8;k++) x[k]=residual[k]*rs;
            idxs[lvl] = scan_fast(x, 2.f/dpow, residual, (lvl<3), flag);
            dpow *= decay;
        }
    }

    // rescue bookkeeping (B is a multiple of TPB in practice; inactive lanes flag=false)
    if (useCompact){
        u64 mask = __ballot(flag);
        if (mask){
            int lane = tid & 63;
            int leader = __builtin_ctzll(mask);
            u32 base = 0;
            if (lane == leader) base = atomicAdd(cnt, (u32)__builtin_popcountll(mask));
            base = __shfl(base, leader, 64);
            if (flag){
                u32 pos = (u32)__builtin_popcountll(mask & ((1ull<<lane)-1ull));
                list[base+pos] = (u32)row;
            }
        }
    } else if (active){
        flags[row] = flag ? 1 : 0;
    }

    __syncthreads();   // obs region reused as per-thread tables
    if (active)
        phaseB(smem + tid*25, qf, idxs[1],idxs[2],idxs[3],idxs[4],idxs[5],idxs[6],idxs[7],
               decay, lemb, bcp, rcpar, bcx, out + (size_t)row*56);
}

// ============ K2: f64 rescue (dense list or flags fallback) ===================
__global__ __launch_bounds__(TPB) void e8_rescue(
    const float* __restrict__ g_obs,
    const float* __restrict__ pw1, const float* __restrict__ pb1,
    const float* __restrict__ pw2, const float* __restrict__ pb2,
    const float* __restrict__ lemb, const float* __restrict__ bcp,
    const float* __restrict__ rcpar, const float* __restrict__ bcx,
    const float* __restrict__ glogdecay,
    const u32* __restrict__ cnt, const u32* __restrict__ list,
    const unsigned char* __restrict__ flags, int useCompact,
    float* __restrict__ out, int B)
{
    __shared__ float smem[TPB*25];
    const int tid = threadIdx.x;
    int row;
    if (useCompact){
        u32 c = *cnt;
        if ((u32)blockIdx.x*TPB >= c) return;
        int gid = blockIdx.x*TPB + tid;
        if (gid >= (int)c) return;
        row = (int)list[gid];
    } else {
        row = blockIdx.x*TPB + tid;
        bool f = (row < B) && (flags[row] != 0);
        if (__ballot(f) == 0ull) return;
        if (!f) return;
    }

    double ob[14];
    #pragma unroll
    for (int j=0;j<14;j++) ob[j] = (double)g_obs[(size_t)row*14+j];
    double qa[8];
    #pragma unroll
    for (int m=0;m<8;m++) qa[m] = (double)pb2[m];
    #pragma unroll 1
    for (int k=0;k<32;k++){
        double a = (double)pb1[k];
        #pragma unroll
        for (int j=0;j<14;j++) a += (double)pw1[k*14+j]*ob[j];
        double hk = 0.5*a*(1.0 + erf(a*0.70710678118654752440));
        #pragma unroll
        for (int m=0;m<8;m++) qa[m] += (double)pw2[m*32+k]*hk;
    }
    double n2 = 0.0;
    #pragma unroll
    for (int m=0;m<8;m++) n2 += qa[m]*qa[m];
    double nr = sqrt(n2); if (nr < 1e-12) nr = 1e-12;
    double q[8], residual[8];
    #pragma unroll
    for (int m=0;m<8;m++){ q[m] = qa[m]/nr*1.4142135623730951; residual[m]=q[m]; }

    double decay_d = exp((double)glogdecay[0]);
    double dpow = 1.0;
    int idxs[8] = {0,0,0,0,0,0,0,0};
    #pragma unroll 1
    for (int lvl=0; lvl<8; ++lvl){
        double rs = 0.5*dpow;
        double x[8];
        #pragma unroll
        for (int k=0;k<8;k++) x[k]=residual[k]*rs;
        int bidx = scan_exact_f64(x);
        apply_root_f64(bidx, 2.0/dpow, residual);
        #pragma unroll
        for (int l2=0;l2<8;l2++) if (l2==lvl) idxs[l2]=bidx;
        dpow *= decay_d;
    }
    float qf[8];
    #pragma unroll
    for (int m=0;m<8;m++) qf[m]=(float)q[m];
    phaseB(smem + tid*25, qf, idxs[1],idxs[2],idxs[3],idxs[4],idxs[5],idxs[6],idxs[7],
           (float)decay_d, lemb, bcp, rcpar, bcx, out + (size_t)row*56);
}

// ============ K3: gated refinement MLP, RMW on out ============================
// out_emb = (emb + sg*b2) + sum_k (sg*gelu_k) * W2[:,k]  -> no rf[52] array.
__global__ __launch_bounds__(TPB) void e8_refine(
    const float* __restrict__ rw1, const float* __restrict__ rb1,
    const float* __restrict__ rw2, const float* __restrict__ rb2,
    const float* __restrict__ rgate,
    float* __restrict__ out, int B)
{
    __shared__ float tbuf[TPB*52];      // stride 52 (4-way conflict, 104 ops -> negligible)
    const int tid = threadIdx.x;
    const int row = blockIdx.x*TPB + tid;
    if (row >= B) return;
    float* T = tbuf + tid*52;
    float* orow = out + (size_t)row*56;
    float emb[52];
    {
        const float4* o4 = (const float4*)orow;
        #pragma unroll
        for (int t=0;t<13;t++){
            float4 v = o4[t];
            emb[4*t]=v.x; emb[4*t+1]=v.y; emb[4*t+2]=v.z; emb[4*t+3]=v.w;
        }
    }
    float sg = 1.f/(1.f+__expf(-rgate[0]));
    #pragma unroll 1
    for (int k=0;k<52;k++){             // pass 1: hidden acts (emb pristine)
        float a = rb1[k];
        #pragma unroll
        for (int j=0;j<52;j++) a = fmaf(rw1[k*52+j], emb[j], a);
        T[k] = sg * 0.5f*a*(1.f+erff(a*0.70710678f));
    }
    #pragma unroll
    for (int m=0;m<52;m++) emb[m] = fmaf(sg, rb2[m], emb[m]);
    #pragma unroll 1
    for (int k=0;k<52;k++){             // pass 2: accumulate straight into emb
        float t = T[k];
        #pragma unroll
        for (int m=0;m<52;m++) emb[m] = fmaf(t, rw2[m*52+k], emb[m]);
    }
    float4* o4 = (float4*)orow;
    #pragma unroll
    for (int t=0;t<13;t++)
        o4[t] = make_float4(emb[4*t], emb[4*t+1], emb[4*t+2], emb[4*t+3]);
    // ctl (o4[13]) untouched
}

extern "C" void kernel_launch(void* const* d_in, const int* in_sizes, int n_in,
                              void* d_out, int out_size, void* d_ws, size_t ws_size,
                              hipStream_t stream)
{
    const float* obs  = (const float*)d_in[0];
    const float* pw1  = (const float*)d_in[1];
    const float* pb1  = (const float*)d_in[2];
    const float* pw2  = (const float*)d_in[3];
    const float* pb2  = (const float*)d_in[4];
    const float* lemb = (const float*)d_in[5];
    const float* bcp  = (const float*)d_in[6];
    const float* rcp  = (const float*)d_in[7];
    const float* bcx  = (const float*)d_in[8];
    const float* ld   = (const float*)d_in[9];
    const float* rw1  = (const float*)d_in[10];
    const float* rb1  = (const float*)d_in[11];
    const float* rw2  = (const float*)d_in[12];
    const float* rb2  = (const float*)d_in[13];
    const float* rg   = (const float*)d_in[14];

    int B = in_sizes[0] / 14;
    int grid = (B + TPB - 1) / TPB;

    bool compact = ws_size >= (size_t)256 + (size_t)B*4;
    u32* cnt  = (u32*)d_ws;
    u32* list = (u32*)d_ws + 64;                 // 256 B offset
    unsigned char* flags = (unsigned char*)d_ws; // fallback layout

    if (compact) hipMemsetAsync(d_ws, 0, 4, stream);   // zero rescue counter

    e8_main<<<grid, TPB, 0, stream>>>(obs, pw1, pb1, pw2, pb2, lemb, bcp, rcp, bcx, ld,
                                      cnt, list, flags, compact?1:0, (float*)d_out, B);
    e8_rescue<<<grid, TPB, 0, stream>>>(obs, pw1, pb1, pw2, pb2, lemb, bcp, rcp, bcx, ld,
                                        cnt, list, flags, compact?1:0, (float*)d_out, B);
    e8_refine<<<grid, TPB, 0, stream>>>(rw1, rb1, rw2, rb2, rg, (float*)d_out, B);
}